// Round 1
// baseline (91.065 us; speedup 1.0000x reference)
//
#include <hip/hip_runtime.h>
#include <math.h>

// Problem geometry
#define NC   65536              // curves
#define NL   256                // points per curve
#define NTOT (NC * NL)          // 16,777,216
#define NBLK 2048               // blocks in main kernel
#define WPB  4                  // waves per block (256 threads)
#define NWAVE (NBLK * WPB)      // 8192 waves
#define CPW  (NC / NWAVE)       // 8 curves per wave
#define NSTAT 10                // partial stats per block

// stat slots: 0=sq 1=reluAp 2=pen 3=sw 4=sx 5=sy 6=sxy 7=sxx 8=syy 9=srd

__global__ __launch_bounds__(256) void loss_main(
    const float* __restrict__ An, const float* __restrict__ Ac,
    const float* __restrict__ Aj, const float* __restrict__ Ap,
    const float* __restrict__ Ar, const float* __restrict__ Ci,
    const float* __restrict__ Vc, const float* __restrict__ Jm,
    const float* __restrict__ Rd, const int* __restrict__ msk,
    float* __restrict__ ws)
{
    const int lane = threadIdx.x & 63;
    const int wid  = threadIdx.x >> 6;
    const int wave = blockIdx.x * WPB + wid;

    // per-lane running accumulators (reduced once at the end)
    float sq = 0.f, rAp = 0.f, pen = 0.f;
    // lane-0-only per-curve stats
    float sw = 0.f, sx = 0.f, sy = 0.f, sxy = 0.f, sxx = 0.f, syy = 0.f, srd = 0.f;

    for (int k = 0; k < CPW; ++k) {
        const int c = wave * CPW + k;
        const size_t base = (size_t)c * NL;
        const size_t off  = base + (size_t)(lane << 2);

        const float4 an = *(const float4*)(An + off);
        const float4 ar = *(const float4*)(Ar + off);
        const float4 ac = *(const float4*)(Ac + off);
        const float4 aj = *(const float4*)(Aj + off);
        const float4 ap = *(const float4*)(Ap + off);

        float lsAj = 0.f, lsAc = 0.f;          // per-curve sums (need wave reduce)
        float bestv = 3.402823466e38f;         // abs-argmin value
        int   besti = 0;                       // linear index in [0,256)
        float aj_at = 0.f, ap_at = 0.f;        // Aj/Ap at argmin

#define PROC(cmp, j)                                                          \
        {                                                                     \
            float d = an.cmp - ar.cmp; sq = fmaf(d, d, sq);                   \
            rAp += fmaxf(-ap.cmp, 0.f);                                       \
            float acj = ac.cmp - aj.cmp;                                      \
            lsAj += fmaxf(-acj, 0.f);                                         \
            lsAc += fmaxf( acj, 0.f);                                         \
            float a = fabsf(acj);                                             \
            if (a < bestv) { bestv = a; besti = (lane << 2) + (j);            \
                             aj_at = aj.cmp; ap_at = ap.cmp; }                \
        }
        PROC(x, 0) PROC(y, 1) PROC(z, 2) PROC(w, 3)
#undef PROC

        // wave butterfly: argmin (first-index tie-break) + two sums
#pragma unroll
        for (int s = 1; s < 64; s <<= 1) {
            float ov  = __shfl_xor(bestv, s);
            int   oi  = __shfl_xor(besti, s);
            float oaj = __shfl_xor(aj_at, s);
            float oap = __shfl_xor(ap_at, s);
            if (ov < bestv || (ov == bestv && oi < besti)) {
                bestv = ov; besti = oi; aj_at = oaj; ap_at = oap;
            }
            float t1 = __shfl_xor(lsAj, s); lsAj += t1;
            float t2 = __shfl_xor(lsAc, s); lsAc += t2;
        }

        if (lane == 63) {
            // end-of-curve penalties: element 255 is this lane's .w component
            float ci_e = Ci[base + 255];
            int   m    = msk[c];
            if (ci_e > 500.f && m == 0)
                pen += 0.15f * fmaxf(ap.w - aj.w, 0.f);
            pen += fmaxf(aj.w - ac.w, 0.f);
        }
        if (lane == 0) {
            int m = msk[c];
            pen += 3.f * fmaxf(1.1f * aj_at - ap_at, 0.f);
            if (m == 0) {
                pen += fmaxf(8.f - lsAj, 0.f) + fmaxf(8.f - lsAc, 0.f);
                float yv = Vc[c], xv = Jm[c];
                sw += 1.f; sy += yv; sx += xv;
                sxy = fmaf(xv, yv, sxy);
                sxx = fmaf(xv, xv, sxx);
                syy = fmaf(yv, yv, syy);
            }
            srd += fmaxf(-Rd[c], 0.f);
        }
    }

    // reduce the three per-lane accumulators across the wave
#pragma unroll
    for (int s = 1; s < 64; s <<= 1) {
        float a = __shfl_xor(sq,  s); sq  += a;
        float b = __shfl_xor(rAp, s); rAp += b;
        float d = __shfl_xor(pen, s); pen += d;
    }

    __shared__ float sred[WPB][NSTAT];
    if (lane == 0) {
        sred[wid][0] = sq;  sred[wid][1] = rAp; sred[wid][2] = pen;
        sred[wid][3] = sw;  sred[wid][4] = sx;  sred[wid][5] = sy;
        sred[wid][6] = sxy; sred[wid][7] = sxx; sred[wid][8] = syy;
        sred[wid][9] = srd;
    }
    __syncthreads();
    if (threadIdx.x == 0) {
#pragma unroll
        for (int j = 0; j < NSTAT; ++j) {
            float v = sred[0][j] + sred[1][j] + sred[2][j] + sred[3][j];
            ws[j * NBLK + blockIdx.x] = v;
        }
    }
}

__global__ __launch_bounds__(256) void loss_final(
    const float* __restrict__ ws,
    const float* __restrict__ dHaV, const float* __restrict__ dHaJ,
    const float* __restrict__ dHaT,
    const float* __restrict__ ToV,  const float* __restrict__ ToJ,
    const float* __restrict__ ToT,
    float* __restrict__ out)
{
    __shared__ float red[NSTAT][256];
    const int t = threadIdx.x;
    float p[NSTAT];
#pragma unroll
    for (int j = 0; j < NSTAT; ++j) p[j] = 0.f;
    for (int k = 0; k < NBLK / 256; ++k) {
        int b = t + k * 256;
#pragma unroll
        for (int j = 0; j < NSTAT; ++j) p[j] += ws[j * NBLK + b];
    }
#pragma unroll
    for (int j = 0; j < NSTAT; ++j) red[j][t] = p[j];
    __syncthreads();
    for (int s = 128; s > 0; s >>= 1) {
        if (t < s) {
#pragma unroll
            for (int j = 0; j < NSTAT; ++j) red[j][t] += red[j][t + s];
        }
        __syncthreads();
    }
    if (t == 0) {
        float sqs = red[0][0], rAp = red[1][0], pen = red[2][0];
        float sw  = red[3][0], sx  = red[4][0], sy  = red[5][0];
        float sxy = red[6][0], sxx = red[7][0], syy = red[8][0];
        float srd = red[9][0];

        float loss = sqs * (10.f / (float)NTOT);

        // Pearson correlation over masked curves (one-pass identity)
        float cnum = sxy - sx * sy / sw;
        float cden = sqrtf(sxx - sx * sx / sw) * sqrtf(syy - sy * sy / sw);
        float cost = cnum / cden;
        if (!(cost == cost)) cost = 0.f;       // NaN -> 0
        cost = fminf(cost, 0.7f);
        loss += 0.7f - cost;

        loss += srd;

        float fg = 0.f;
#pragma unroll
        for (int i = 0; i < 4; ++i) {
            fg += 10.f * fmaxf(-dHaV[i], 0.f);
            fg += fmaxf(-dHaJ[i], 0.f);
            fg += fmaxf(-dHaT[i], 0.f);
            fg += fmaxf(273.15f - ToV[i], 0.f);
            fg += fmaxf(273.15f - ToJ[i], 0.f);
            fg += fmaxf(273.15f - ToT[i], 0.f);
        }
        loss += fg;

        loss += rAp;   // sum relu(-Ap_o) over all N
        loss += pen;   // end-of-curve + per-curve penalties

        out[0] = loss;
    }
}

extern "C" void kernel_launch(void* const* d_in, const int* in_sizes, int n_in,
                              void* d_out, int out_size, void* d_ws, size_t ws_size,
                              hipStream_t stream) {
    const float* An  = (const float*)d_in[0];
    const float* Ac  = (const float*)d_in[1];
    const float* Aj  = (const float*)d_in[2];
    const float* Ap  = (const float*)d_in[3];
    const float* Ar  = (const float*)d_in[4];
    const float* Ci  = (const float*)d_in[5];
    const float* Vc  = (const float*)d_in[6];
    const float* Jm  = (const float*)d_in[7];
    const float* Rd  = (const float*)d_in[8];
    const float* dHaV = (const float*)d_in[9];
    const float* dHaJ = (const float*)d_in[10];
    const float* dHaT = (const float*)d_in[11];
    const float* ToV  = (const float*)d_in[12];
    const float* ToJ  = (const float*)d_in[13];
    const float* ToT  = (const float*)d_in[14];
    const int*   msk  = (const int*)d_in[15];

    float* ws  = (float*)d_ws;           // NSTAT * NBLK floats = 80 KB
    float* out = (float*)d_out;

    loss_main<<<NBLK, 256, 0, stream>>>(An, Ac, Aj, Ap, Ar, Ci, Vc, Jm, Rd, msk, ws);
    loss_final<<<1, 256, 0, stream>>>(ws, dHaV, dHaJ, dHaT, ToV, ToJ, ToT, out);
}

// Round 2
// 66.164 us; speedup vs baseline: 1.3763x; 1.3763x over previous
//
#include <hip/hip_runtime.h>
#include <math.h>

// Problem geometry
#define NC   65536              // curves
#define NL   256                // points per curve
#define NTOT (NC * NL)
#define CPW  16                 // curves per wave
#define WPB  4                  // waves per block (256 threads)
#define NBLK (NC / (CPW * WPB)) // 1024 blocks
#define NSTAT 10

// stat slots: 0=sq 1=reluAp 2=pen 3=sw 4=sx 5=sy 6=sxy 7=sxx 8=syy 9=srd

__global__ __launch_bounds__(256) void loss_main(
    const float* __restrict__ An, const float* __restrict__ Ac,
    const float* __restrict__ Aj, const float* __restrict__ Ap,
    const float* __restrict__ Ar, const float* __restrict__ Ci,
    const float* __restrict__ Vc, const float* __restrict__ Jm,
    const float* __restrict__ Rd, const int* __restrict__ msk,
    float* __restrict__ ws)
{
    const int lane = threadIdx.x & 63;
    const int wid  = threadIdx.x >> 6;
    const int l    = lane & 15;          // lane within 16-lane group
    const int g    = lane >> 4;          // group id 0..3 (curve within quad)
    const int c0   = (blockIdx.x * WPB + wid) * CPW;   // first curve of wave

    // ---- per-curve preload: lane i (<16) owns curve c0+i ----
    float wmask = 0.f, fitw = 0.f;
    float sw=0.f, sx=0.f, sy=0.f, sxy=0.f, sxx=0.f, syy=0.f, srd=0.f;
    if (lane < CPW) {
        const int c = c0 + lane;
        const int m = msk[c];
        const float x = Jm[c], y = Vc[c], rd = Rd[c];
        const float ci = Ci[(size_t)c * NL + (NL - 1)];
        wmask = (m == 0) ? 1.f : 0.f;
        fitw  = (ci > 500.f) ? 0.15f * wmask : 0.f;
        srd   = fmaxf(-rd, 0.f);
        sw = wmask; sx = wmask * x; sy = wmask * y;
        sxy = wmask * x * y; sxx = wmask * x * x; syy = wmask * y * y;
    }

    float sq = 0.f, rAp = 0.f, pen = 0.f;

#pragma unroll 1
    for (int k = 0; k < CPW / 4; ++k) {
        const int c = c0 + k * 4 + g;
        const size_t off = (size_t)c * NL + (size_t)(l << 2);
        const float4* pAn = (const float4*)(An + off);
        const float4* pAr = (const float4*)(Ar + off);
        const float4* pAc = (const float4*)(Ac + off);
        const float4* pAj = (const float4*)(Aj + off);
        const float4* pAp = (const float4*)(Ap + off);
        // 20 independent float4 loads (lane covers elements j*64 + l*4 + 0..3)
        float4 an0=pAn[0], an1=pAn[16], an2=pAn[32], an3=pAn[48];
        float4 ar0=pAr[0], ar1=pAr[16], ar2=pAr[32], ar3=pAr[48];
        float4 ac0=pAc[0], ac1=pAc[16], ac2=pAc[32], ac3=pAc[48];
        float4 aj0=pAj[0], aj1=pAj[16], aj2=pAj[32], aj3=pAj[48];
        float4 ap0=pAp[0], ap1=pAp[16], ap2=pAp[32], ap3=pAp[48];

        float lsAj = 0.f, lsAc = 0.f;
        float bestv = 3.402823466e38f; int besti = 0;
        float aj_at = 0.f, ap_at = 0.f;

#define PR(AN,AR,AC,AJ,AP,CMP,JJ,CC)                                   \
        { float d = AN.CMP - AR.CMP; sq = fmaf(d, d, sq);              \
          rAp += fmaxf(-AP.CMP, 0.f);                                  \
          float acj = AC.CMP - AJ.CMP;                                 \
          lsAj += fmaxf(-acj, 0.f); lsAc += fmaxf(acj, 0.f);           \
          float a = fabsf(acj);                                        \
          if (a < bestv) { bestv = a; besti = (JJ)*64 + (l<<2) + (CC); \
                           aj_at = AJ.CMP; ap_at = AP.CMP; } }
        PR(an0,ar0,ac0,aj0,ap0,x,0,0) PR(an0,ar0,ac0,aj0,ap0,y,0,1)
        PR(an0,ar0,ac0,aj0,ap0,z,0,2) PR(an0,ar0,ac0,aj0,ap0,w,0,3)
        PR(an1,ar1,ac1,aj1,ap1,x,1,0) PR(an1,ar1,ac1,aj1,ap1,y,1,1)
        PR(an1,ar1,ac1,aj1,ap1,z,1,2) PR(an1,ar1,ac1,aj1,ap1,w,1,3)
        PR(an2,ar2,ac2,aj2,ap2,x,2,0) PR(an2,ar2,ac2,aj2,ap2,y,2,1)
        PR(an2,ar2,ac2,aj2,ap2,z,2,2) PR(an2,ar2,ac2,aj2,ap2,w,2,3)
        PR(an3,ar3,ac3,aj3,ap3,x,3,0) PR(an3,ar3,ac3,aj3,ap3,y,3,1)
        PR(an3,ar3,ac3,aj3,ap3,z,3,2) PR(an3,ar3,ac3,aj3,ap3,w,3,3)
#undef PR

        // 4-stage butterfly within the 16-lane group: argmin + two sums
#pragma unroll
        for (int s = 1; s < 16; s <<= 1) {
            float ov  = __shfl_xor(bestv, s);
            int   oi  = __shfl_xor(besti, s);
            float oaj = __shfl_xor(aj_at, s);
            float oap = __shfl_xor(ap_at, s);
            if (ov < bestv || (ov == bestv && oi < besti)) {
                bestv = ov; besti = oi; aj_at = oaj; ap_at = oap;
            }
            lsAj += __shfl_xor(lsAj, s);
            lsAc += __shfl_xor(lsAc, s);
        }

        // fetch this curve's mask weights from the preload lanes (uniform per group)
        const int srcl = k * 4 + g;
        const float wv = __shfl(wmask, srcl);
        const float fw = __shfl(fitw,  srcl);

        if (l == 0) {
            pen += 3.f * fmaxf(1.1f * aj_at - ap_at, 0.f);
            pen += wv * (fmaxf(8.f - lsAj, 0.f) + fmaxf(8.f - lsAc, 0.f));
        }
        if (l == 15) {   // holds elements 252..255; end = .w of j=3
            pen += fmaxf(aj3.w - ac3.w, 0.f);
            pen += fw * fmaxf(ap3.w - aj3.w, 0.f);
        }
    }

    // ---- wave-wide reduction of the 10 stats ----
    float st[NSTAT] = {sq, rAp, pen, sw, sx, sy, sxy, sxx, syy, srd};
#pragma unroll
    for (int j = 0; j < NSTAT; ++j) {
#pragma unroll
        for (int s = 1; s < 64; s <<= 1) st[j] += __shfl_xor(st[j], s);
    }

    __shared__ float sred[WPB][NSTAT];
    if (lane == 0) {
#pragma unroll
        for (int j = 0; j < NSTAT; ++j) sred[wid][j] = st[j];
    }
    __syncthreads();
    if (threadIdx.x == 0) {
#pragma unroll
        for (int j = 0; j < NSTAT; ++j) {
            float v = sred[0][j] + sred[1][j] + sred[2][j] + sred[3][j];
            ws[j * NBLK + blockIdx.x] = v;
        }
    }
}

__global__ __launch_bounds__(256) void loss_final(
    const float* __restrict__ ws,
    const float* __restrict__ dHaV, const float* __restrict__ dHaJ,
    const float* __restrict__ dHaT,
    const float* __restrict__ ToV,  const float* __restrict__ ToJ,
    const float* __restrict__ ToT,
    float* __restrict__ out)
{
    __shared__ float red[NSTAT][256];
    const int t = threadIdx.x;
    float p[NSTAT];
#pragma unroll
    for (int j = 0; j < NSTAT; ++j) p[j] = 0.f;
    for (int k = 0; k < NBLK / 256; ++k) {
        int b = t + k * 256;
#pragma unroll
        for (int j = 0; j < NSTAT; ++j) p[j] += ws[j * NBLK + b];
    }
#pragma unroll
    for (int j = 0; j < NSTAT; ++j) red[j][t] = p[j];
    __syncthreads();
    for (int s = 128; s > 0; s >>= 1) {
        if (t < s) {
#pragma unroll
            for (int j = 0; j < NSTAT; ++j) red[j][t] += red[j][t + s];
        }
        __syncthreads();
    }
    if (t == 0) {
        float sqs = red[0][0], rAp = red[1][0], pen = red[2][0];
        float sw  = red[3][0], sx  = red[4][0], sy  = red[5][0];
        float sxy = red[6][0], sxx = red[7][0], syy = red[8][0];
        float srd = red[9][0];

        float loss = sqs * (10.f / (float)NTOT);

        // Pearson correlation over masked curves (one-pass identity)
        float cnum = sxy - sx * sy / sw;
        float cden = sqrtf(sxx - sx * sx / sw) * sqrtf(syy - sy * sy / sw);
        float cost = cnum / cden;
        if (!(cost == cost)) cost = 0.f;       // NaN -> 0
        cost = fminf(cost, 0.7f);
        loss += 0.7f - cost;

        loss += srd;

        float fg = 0.f;
#pragma unroll
        for (int i = 0; i < 4; ++i) {
            fg += 10.f * fmaxf(-dHaV[i], 0.f);
            fg += fmaxf(-dHaJ[i], 0.f);
            fg += fmaxf(-dHaT[i], 0.f);
            fg += fmaxf(273.15f - ToV[i], 0.f);
            fg += fmaxf(273.15f - ToJ[i], 0.f);
            fg += fmaxf(273.15f - ToT[i], 0.f);
        }
        loss += fg;

        loss += rAp;   // sum relu(-Ap_o) over all N
        loss += pen;   // end-of-curve + per-curve penalties

        out[0] = loss;
    }
}

extern "C" void kernel_launch(void* const* d_in, const int* in_sizes, int n_in,
                              void* d_out, int out_size, void* d_ws, size_t ws_size,
                              hipStream_t stream) {
    const float* An  = (const float*)d_in[0];
    const float* Ac  = (const float*)d_in[1];
    const float* Aj  = (const float*)d_in[2];
    const float* Ap  = (const float*)d_in[3];
    const float* Ar  = (const float*)d_in[4];
    const float* Ci  = (const float*)d_in[5];
    const float* Vc  = (const float*)d_in[6];
    const float* Jm  = (const float*)d_in[7];
    const float* Rd  = (const float*)d_in[8];
    const float* dHaV = (const float*)d_in[9];
    const float* dHaJ = (const float*)d_in[10];
    const float* dHaT = (const float*)d_in[11];
    const float* ToV  = (const float*)d_in[12];
    const float* ToJ  = (const float*)d_in[13];
    const float* ToT  = (const float*)d_in[14];
    const int*   msk  = (const int*)d_in[15];

    float* ws  = (float*)d_ws;           // NSTAT * NBLK floats = 40 KB
    float* out = (float*)d_out;

    loss_main<<<NBLK, 256, 0, stream>>>(An, Ac, Aj, Ap, Ar, Ci, Vc, Jm, Rd, msk, ws);
    loss_final<<<1, 256, 0, stream>>>(ws, dHaV, dHaJ, dHaT, ToV, ToJ, ToT, out);
}